// Round 11
// baseline (110.769 us; speedup 1.0000x reference)
//
#include <hip/hip_runtime.h>
#include <hip/hip_bf16.h>
#include <cmath>

typedef unsigned short u16;
typedef __attribute__((ext_vector_type(8))) short s8v;    // 8 x bf16 bits
typedef __attribute__((ext_vector_type(4))) float f4v;
typedef __attribute__((ext_vector_type(2))) float f2v;
typedef __attribute__((ext_vector_type(4))) unsigned int u32x4;
typedef __attribute__((ext_vector_type(4))) unsigned short u16x4;

#define MFMA(a,b,c) __builtin_amdgcn_mfma_f32_16x16x32_bf16((a),(b),(c),0,0,0)

__device__ __forceinline__ float bf2f(u16 u) {
    union { float f; unsigned i; } x; x.i = ((unsigned)u) << 16; return x.f;
}
__device__ __forceinline__ u16 f2bf(float f) {
    union { float f; unsigned i; } x; x.f = f;
    unsigned r = x.i + 0x7FFFu + ((x.i >> 16) & 1u);
    return (u16)(r >> 16);
}
__device__ __forceinline__ unsigned cvtpk(float lo, float hi) {
    unsigned r;
    asm("v_cvt_pk_bf16_f32 %0, %1, %2" : "=v"(r) : "v"(lo), "v"(hi));
    return r;
}
__device__ __forceinline__ void gload_lds16(const void* g, void* l) {
    __builtin_amdgcn_global_load_lds(
        (const __attribute__((address_space(1))) unsigned int*)g,
        (__attribute__((address_space(3))) unsigned int*)l, 16, 0, 0);
}
// swizzled byte offset into a [128 rows][128 B] LDS tile; bijective per row,
// write and read sides both conflict-free (2-way max)
__device__ __forceinline__ int swb(int row, int colb) {
    return row * 128 + (colb ^ ((((row >> 4) ^ row) & 7) << 4));
}

// chunks-per-qblock and per-p-tile prefix (512-key chunks, block-causal)
__constant__ int CPER[8]  = {1,1,2,2,3,3,4,4};
__constant__ int POFF[17] = {0,1,2,3,4,6,8,10,12,15,18,21,24,28,32,36,40};

// ---------------------------------------------------------------------------
// Kernel 1: fused QKV projection (f32 in -> bf16 MFMA -> bf16 out).
// Q output PRESCALED by 0.125*log2(e). Q,K: [b][h][T][d]; V: VT [b][h][d][T].
// XCD-chunked block map; swizzled LDS; T14 reg-prefetch; staging via 2x8
// register micro-transpose: 8 dwordx2 loads -> 4 cvtpk -> 1 b128 write/row.
// ---------------------------------------------------------------------------
__global__ __launch_bounds__(256)
void qkv_proj(const float* __restrict__ q, const float* __restrict__ kv,
              const float* __restrict__ Wq, const float* __restrict__ bq,
              const float* __restrict__ Wkv, const float* __restrict__ bkv,
              u16* __restrict__ QH, u16* __restrict__ KH, u16* __restrict__ VT)
{
    __shared__ __align__(16) u16 Al[128 * 64];
    __shared__ __align__(16) u16 Bl[128 * 64];

    const int bid = blockIdx.x;
    const int x = bid & 7, i = bid >> 3;     // XCD-chunked: same-mt consecutive
    const int mt = x + 8 * (i / 12);
    const int nt = i % 12;
    const int m0 = mt << 7, n0 = nt << 7;

    const int tid  = threadIdx.x;
    const int lane = tid & 63;
    const int w    = tid >> 6;
    const int wr = (w >> 1) * 64, wc = (w & 1) * 64;
    const int cl = lane & 15, rl = lane >> 4;

    const int bb  = m0 >> 11;
    const int t0  = m0 & 2047;
    const int vv  = t0 >> 8;
    const int hw0 = t0 & 255;

    const float* Abase = ((nt < 4) ? q : kv) + (size_t)(vv * 4 + bb) * 131072 + hw0;

    const float* W; const float* bias; int NW, wn0, dn0; u16* dst;
    if (nt < 4)      { W = Wq;  bias = bq;  NW = 512;  wn0 = n0;       dn0 = n0;        dst = QH; }
    else if (nt < 8) { W = Wkv; bias = bkv; NW = 1024; wn0 = n0 - 512; dn0 = n0 - 512;  dst = KH; }
    else             { W = Wkv; bias = bkv; NW = 1024; wn0 = n0 - 512; dn0 = n0 - 1024; dst = VT; }

    const float oscale = (nt < 4) ? 0.18033688011f : 1.0f;  // 0.125*log2(e)

    f4v acc[4][4] = {};
    f2v la[8], lb[8];                 // 2-row x 8-k staging patch (A and B)

    const int mh = tid & 63;          // row pair: rows 2*mh, 2*mh+1
    const int kb = tid >> 6;          // k-oct within BK=32: 0..3

#define QKV_LOAD(k0_) do {                                                   \
        const float* gA = Abase + (size_t)((k0_) + kb * 8) * 256 + mh * 2;   \
        const float* gB = W + (size_t)((k0_) + kb * 8) * NW + wn0 + mh * 2;  \
        _Pragma("unroll")                                                    \
        for (int j = 0; j < 8; ++j) {                                        \
            la[j] = *reinterpret_cast<const f2v*>(gA + j * 256);             \
            lb[j] = *reinterpret_cast<const f2v*>(gB + (size_t)j * NW);      \
        }                                                                    \
    } while (0)

    QKV_LOAD(0);

    for (int k0 = 0; k0 < 512; k0 += 32) {
        #pragma unroll
        for (int e = 0; e < 2; ++e) {        // register micro-transpose
            u32x4 pa, pb;
            #pragma unroll
            for (int jj = 0; jj < 4; ++jj) {
                pa[jj] = cvtpk(la[jj * 2][e], la[jj * 2 + 1][e]);
                pb[jj] = cvtpk(lb[jj * 2][e], lb[jj * 2 + 1][e]);
            }
            *(u32x4*)((char*)Al + swb(mh * 2 + e, kb * 16)) = pa;
            *(u32x4*)((char*)Bl + swb(mh * 2 + e, kb * 16)) = pb;
        }
        __syncthreads();
        if (k0 + 32 < 512) QKV_LOAD(k0 + 32);   // latency hides under MFMA

        s8v af[4], bf[4];
        #pragma unroll
        for (int mi = 0; mi < 4; ++mi)
            af[mi] = *(const s8v*)((const char*)Al + swb(wr + mi * 16 + cl, rl * 16));
        #pragma unroll
        for (int ni = 0; ni < 4; ++ni)
            bf[ni] = *(const s8v*)((const char*)Bl + swb(wc + ni * 16 + cl, rl * 16));
        #pragma unroll
        for (int mi = 0; mi < 4; ++mi)
            #pragma unroll
            for (int ni = 0; ni < 4; ++ni)
                acc[mi][ni] = MFMA(af[mi], bf[ni], acc[mi][ni]);
        __syncthreads();
    }
#undef QKV_LOAD

    if (nt < 8) {
        #pragma unroll
        for (int ni = 0; ni < 4; ++ni) {
            const int nl   = wc + ni * 16 + cl;
            const float bv = bias[wn0 + nl];
            const int cout = dn0 + nl;
            const int hh = cout >> 6, dd = cout & 63;
            const size_t obase = ((size_t)(bb * 8 + hh) * 2048) * 64 + dd;
            #pragma unroll
            for (int mi = 0; mi < 4; ++mi)
                #pragma unroll
                for (int r = 0; r < 4; ++r) {
                    const int m = m0 + wr + mi * 16 + rl * 4 + r;
                    const int t = m & 2047;
                    dst[obase + (size_t)t * 64] = f2bf((acc[mi][ni][r] + bv) * oscale);
                }
        }
    } else {
        #pragma unroll
        for (int ni = 0; ni < 4; ++ni) {
            const int nl   = wc + ni * 16 + cl;
            const float bv = bias[wn0 + nl];
            const int cout = dn0 + nl;
            const int hh = cout >> 6, dd = cout & 63;
            const size_t obase = ((size_t)(bb * 8 + hh) * 64 + dd) * 2048;
            #pragma unroll
            for (int mi = 0; mi < 4; ++mi) {
                const int m = m0 + wr + mi * 16 + rl * 4;
                const int t = m & 2047;
                u16x4 pk;
                #pragma unroll
                for (int r = 0; r < 4; ++r) pk[r] = f2bf(acc[mi][ni][r] + bv);
                *reinterpret_cast<u16x4*>(dst + obase + t) = pk;
            }
        }
    }
}

// ---------------------------------------------------------------------------
// Kernel 2a: attention partials. WG = (bh, 128-row q-tile p, 512-key chunk c).
// Fixed-max softmax; KVBLK=64; gload_lds with pre-swizzled source.
// ---------------------------------------------------------------------------
__global__ __launch_bounds__(256, 3)
void attn_part(const u16* __restrict__ QH, const u16* __restrict__ KH,
               const u16* __restrict__ VT,
               u16* __restrict__ Opart, float* __restrict__ ML)
{
    __shared__ __align__(16) u16 Kl[2][4096];  // [64 key][64 d], byte^=(key&7)<<4
    __shared__ __align__(16) u16 Vl[2][4096];  // [64 d][64 key], byte^=(d&7)<<4
    __shared__ u16 Pl[4][32][36];              // per-wave 32-key P slice

    const int wg = blockIdx.x;
    const int bh = wg & 31;
    const int s  = 39 - (wg >> 5);        // heavy (512-key) chunks first
    int p = 0;
    #pragma unroll
    for (int i = 0; i < 15; ++i) p += (s >= POFF[i + 1]) ? 1 : 0;
    const int c  = s - POFF[p];
    const int qb = p >> 1;
    const int kstart = c * 512;
    const int nk = min(512, (qb + 1) * 256 - kstart);
    const int nt64 = nk >> 6;             // 4 or 8 key tiles of 64

    const int tid = threadIdx.x, lane = tid & 63, w = tid >> 6;
    const int cl = lane & 15, rl = lane >> 4;

    const u16* Qb = QH + (size_t)bh * 131072;
    const u16* Kb = KH + (size_t)bh * 131072;
    const u16* Vb = VT + (size_t)bh * 131072;

    const int qrow0 = p * 128 + w * 32;

    s8v qf[2][2];
    #pragma unroll
    for (int mi = 0; mi < 2; ++mi)
        #pragma unroll
        for (int kf = 0; kf < 2; ++kf)
            qf[mi][kf] = *reinterpret_cast<const s8v*>(
                Qb + (size_t)(qrow0 + mi * 16 + cl) * 64 + kf * 32 + rl * 8);

    // per-thread pre-swizzled source offsets (slot f = w*128 + i*64 + lane)
    unsigned kofs[2], vofs[2];
    #pragma unroll
    for (int i = 0; i < 2; ++i) {
        const int f = w * 128 + i * 64 + lane;
        const int row = f >> 3;
        kofs[i] = row * 128 + (((f & 7) * 16) ^ ((row & 7) << 4));
        vofs[i] = row * 4096 + (((f & 7) * 16) ^ ((row & 7) << 4));
    }

#define ISSUE(bufi, kb0_) do {                                               \
        const char* kG = (const char*)Kb + (size_t)(kb0_) * 128;             \
        const char* vG = (const char*)Vb + (size_t)(kb0_) * 2;               \
        char* kL = (char*)&Kl[bufi][0] + w * 2048;                           \
        char* vL = (char*)&Vl[bufi][0] + w * 2048;                           \
        _Pragma("unroll")                                                    \
        for (int i_ = 0; i_ < 2; ++i_) {                                     \
            gload_lds16(kG + kofs[i_], kL + i_ * 1024);                      \
            gload_lds16(vG + vofs[i_], vL + i_ * 1024);                      \
        }                                                                    \
    } while (0)

    f4v o[2][4] = {};
    float lp[8] = {0.f, 0.f, 0.f, 0.f, 0.f, 0.f, 0.f, 0.f};

    ISSUE(0, kstart);

    for (int kt = 0; kt < nt64; ++kt) {
        asm volatile("s_waitcnt vmcnt(0)" ::: "memory");
        __builtin_amdgcn_sched_barrier(0);
        __syncthreads();
        if (kt + 1 < nt64) ISSUE((kt + 1) & 1, kstart + (kt + 1) * 64);

        const char* Kbase = (const char*)&Kl[kt & 1][0];
        const char* Vbase = (const char*)&Vl[kt & 1][0];

        // S = Q K^T (swizzled LDS reads)
        f4v sc[2][4] = {};
        #pragma unroll
        for (int ni = 0; ni < 4; ++ni)
            #pragma unroll
            for (int kf = 0; kf < 2; ++kf) {
                const int row = ni * 16 + cl;
                s8v kfr = *reinterpret_cast<const s8v*>(
                    Kbase + row * 128 + ((kf * 64 + rl * 16) ^ ((row & 7) << 4)));
                sc[0][ni] = MFMA(qf[0][kf], kfr, sc[0][ni]);
                sc[1][ni] = MFMA(qf[1][kf], kfr, sc[1][ni]);
            }

        // fixed-max softmax: P = exp2(s) directly (s bounded, Q prescaled)
        #pragma unroll
        for (int mi = 0; mi < 2; ++mi)
            #pragma unroll
            for (int ni = 0; ni < 4; ++ni)
                #pragma unroll
                for (int r = 0; r < 4; ++r)
                    sc[mi][ni][r] = exp2f(sc[mi][ni][r]);
        #pragma unroll
        for (int mi = 0; mi < 2; ++mi)
            #pragma unroll
            for (int r = 0; r < 4; ++r)
                lp[mi * 4 + r] += sc[mi][0][r] + sc[mi][1][r]
                                + sc[mi][2][r] + sc[mi][3][r];

        // PV in two 32-key windows through per-wave LDS
        #pragma unroll
        for (int kw = 0; kw < 2; ++kw) {
            #pragma unroll
            for (int mi = 0; mi < 2; ++mi)
                #pragma unroll
                for (int jj = 0; jj < 2; ++jj) {
                    const int ni = kw * 2 + jj;
                    const unsigned w0 = cvtpk(sc[mi][ni][0], sc[mi][ni][1]);
                    const unsigned w1 = cvtpk(sc[mi][ni][2], sc[mi][ni][3]);
                    const int col = jj * 16 + cl;
                    Pl[w][mi * 16 + rl * 4 + 0][col] = (u16)w0;
                    Pl[w][mi * 16 + rl * 4 + 1][col] = (u16)(w0 >> 16);
                    Pl[w][mi * 16 + rl * 4 + 2][col] = (u16)w1;
                    Pl[w][mi * 16 + rl * 4 + 3][col] = (u16)(w1 >> 16);
                }
            s8v pf0 = *reinterpret_cast<const s8v*>(&Pl[w][cl][rl * 8]);
            s8v pf1 = *reinterpret_cast<const s8v*>(&Pl[w][16 + cl][rl * 8]);
            #pragma unroll
            for (int di = 0; di < 4; ++di) {
                const int row = di * 16 + cl;
                s8v vf = *reinterpret_cast<const s8v*>(
                    Vbase + row * 128 + ((kw * 64 + rl * 16) ^ ((row & 7) << 4)));
                o[0][di] = MFMA(pf0, vf, o[0][di]);
                o[1][di] = MFMA(pf1, vf, o[1][di]);
            }
        }
    }
#undef ISSUE

    // write partial: Ohat = O/l (bf16), l (f32)
    const int slot = bh * 40 + POFF[p] + c;
    #pragma unroll
    for (int mi = 0; mi < 2; ++mi)
        #pragma unroll
        for (int r = 0; r < 4; ++r) {
            const int idx = mi * 4 + r;
            float ls = lp[idx];
            ls += __shfl_xor(ls, 1);
            ls += __shfl_xor(ls, 2);
            ls += __shfl_xor(ls, 4);
            ls += __shfl_xor(ls, 8);
            const float inv = 1.f / ls;
            const int rloc = w * 32 + mi * 16 + rl * 4 + r;
            if (cl == 0) ML[(size_t)slot * 128 + rloc] = ls;
            #pragma unroll
            for (int di = 0; di < 4; ++di)
                Opart[(size_t)slot * 8192 + rloc * 64 + di * 16 + cl] =
                    f2bf(o[mi][di][r] * inv);
        }
}

// ---------------------------------------------------------------------------
// Kernel 2b: combine partials -> YH [b][t][c] bf16. weights = l_c / sum l_c.
// ---------------------------------------------------------------------------
__global__ __launch_bounds__(256)
void attn_combine(const u16* __restrict__ Opart, const float* __restrict__ ML,
                  u16* __restrict__ YH)
{
    const int wg = blockIdx.x;
    const int bh = wg & 31;
    const int p  = wg >> 5;
    const int b = bh >> 3, h = bh & 7;
    const int nc = CPER[p >> 1];
    const int sb = bh * 40 + POFF[p];

    const int t = threadIdx.x;
    const int rloc = t >> 1;
    const int dh = (t & 1) * 32;

    float lc[4], L = 0.f;
    for (int c = 0; c < nc; ++c) {
        lc[c] = ML[(size_t)(sb + c) * 128 + rloc];
        L += lc[c];
    }
    const float invL = 1.f / L;
    float wgt[4];
    for (int c = 0; c < nc; ++c) wgt[c] = lc[c] * invL;

    f4v a[8] = {};
    for (int c = 0; c < nc; ++c) {
        const float wv = wgt[c];
        #pragma unroll
        for (int u = 0; u < 4; ++u) {
            s8v vv = *reinterpret_cast<const s8v*>(
                &Opart[(size_t)(sb + c) * 8192 + rloc * 64 + dh + u * 8]);
            #pragma unroll
            for (int e = 0; e < 4; ++e) a[u * 2][e]     += wv * bf2f((u16)vv[e]);
            #pragma unroll
            for (int e = 0; e < 4; ++e) a[u * 2 + 1][e] += wv * bf2f((u16)vv[e + 4]);
        }
    }

    const size_t ybase = ((size_t)b * 2048 + p * 128 + rloc) * 512 + h * 64 + dh;
    #pragma unroll
    for (int u = 0; u < 4; ++u) {
        s8v ov;
        #pragma unroll
        for (int e = 0; e < 4; ++e) ov[e]     = (short)f2bf(a[u * 2][e]);
        #pragma unroll
        for (int e = 0; e < 4; ++e) ov[e + 4] = (short)f2bf(a[u * 2 + 1][e]);
        *reinterpret_cast<s8v*>(YH + ybase + u * 8) = ov;
    }
}

// ---------------------------------------------------------------------------
// Kernel 3: output projection (transposed): C'[c][tok] = Wp^T . Y^T.
// Wp staged via 2x8 register micro-transpose (b128 writes); T14 pipeline.
// ---------------------------------------------------------------------------
__global__ __launch_bounds__(256)
void out_proj(const u16* __restrict__ YH, const float* __restrict__ Wp,
              const float* __restrict__ bp, float* __restrict__ out)
{
    __shared__ __align__(16) u16 Al[128 * 64];   // Wp^T tile, swizzled
    __shared__ u16 Bl[128][40];                  // Y tile (linear b128 write)

    const int bid = blockIdx.x;
    const int x = bid & 7, i = bid >> 3;         // 256 blocks
    const int mt = x + 8 * (i >> 2);
    const int ct = i & 3;
    const int c0 = ct << 7, m0 = mt << 7;

    const int tid = threadIdx.x, lane = tid & 63, w = tid >> 6;
    const int wr = (w >> 1) * 64, wc = (w & 1) * 64;
    const int cl = lane & 15, rl = lane >> 4;

    f4v acc[4][4] = {};
    f2v wa[8];
    s8v sy[2];

    const int mh = tid & 63;          // cout pair: rows 2*mh, 2*mh+1
    const int kb = tid >> 6;          // k-oct: 0..3
    const int br = tid >> 2;
    const int bq4 = (tid & 3) * 8;

#define OP_LOAD(k0_) do {                                                    \
        const float* gA = Wp + (size_t)((k0_) + kb * 8) * 512 + c0 + mh * 2; \
        _Pragma("unroll")                                                    \
        for (int j = 0; j < 8; ++j)                                          \
            wa[j] = *reinterpret_cast<const f2v*>(gA + j * 512);             \
        _Pragma("unroll")                                                    \
        for (int it = 0; it < 2; ++it)                                       \
            sy[it] = *reinterpret_cast<const s8v*>(                          \
                YH + (size_t)(m0 + br + it * 64) * 512 + (k0_) + bq4);       \
    } while (0)

    OP_LOAD(0);

    for (int k0 = 0; k0 < 512; k0 += 32) {
        #pragma unroll
        for (int e = 0; e < 2; ++e) {
            u32x4 pa;
            #pragma unroll
            for (int jj = 0; jj < 4; ++jj)
                pa[jj] = cvtpk(wa[jj * 2][e], wa[jj * 2 + 1][e]);
            *(u32x4*)((char*)Al + swb(mh * 2 + e, kb * 16)) = pa;
        }
        #pragma unroll
        for (int it = 0; it < 2; ++it)
            *reinterpret_cast<s8v*>(&Bl[br + it * 64][bq4]) = sy[it];
        __syncthreads();
        if (k0 + 32 < 512) OP_LOAD(k0 + 32);

        s8v af[4], bfr[4];
        #pragma unroll
        for (int mi = 0; mi < 4; ++mi)
            af[mi] = *(const s8v*)((const char*)Al + swb(wr + mi * 16 + cl, rl * 16));
        #pragma unroll
        for (int ni = 0; ni < 4; ++ni)
            bfr[ni] = *reinterpret_cast<const s8v*>(&Bl[wc + ni * 16 + cl][rl * 8]);
        #pragma unroll
        for (int mi = 0; mi < 4; ++mi)
            #pragma unroll
            for (int ni = 0; ni < 4; ++ni)
                acc[mi][ni] = MFMA(af[mi], bfr[ni], acc[mi][ni]);
        __syncthreads();
    }
#undef OP_LOAD

    #pragma unroll
    for (int mi = 0; mi < 4; ++mi)
        #pragma unroll
        for (int r = 0; r < 4; ++r) {
            const int c = c0 + wr + mi * 16 + rl * 4 + r;   // D row = cout
            const float bv = bp[c];
            #pragma unroll
            for (int ni = 0; ni < 4; ++ni) {
                const int tok = m0 + wc + ni * 16 + cl;     // D col = token
                const int bb = tok >> 11, t = tok & 2047;
                const int vv = t >> 8, hw = t & 255;
                out[(size_t)(vv * 4 + bb) * 131072 + (size_t)c * 256 + hw] =
                    acc[mi][ni][r] + bv;
            }
        }
}

// ---------------------------------------------------------------------------
extern "C" void kernel_launch(void* const* d_in, const int* in_sizes, int n_in,
                              void* d_out, int out_size, void* d_ws, size_t ws_size,
                              hipStream_t stream)
{
    const float* q   = (const float*)d_in[0];
    const float* kv  = (const float*)d_in[1];
    const float* Wq  = (const float*)d_in[2];
    const float* bq  = (const float*)d_in[3];
    const float* Wkv = (const float*)d_in[4];
    const float* bkv = (const float*)d_in[5];
    const float* Wp  = (const float*)d_in[6];
    const float* bp  = (const float*)d_in[7];
    float* out = (float*)d_out;

    u16* ws = (u16*)d_ws;
    u16* QH = ws;                    // [4][8][2048][64] bf16, prescaled Q
    u16* KH = QH + 4194304;          // [4][8][2048][64]
    u16* VT = KH + 4194304;          // [4][8][64][2048]
    u16* YH = VT + 4194304;          // [4][2048][512]
    u16* Opart = YH + 4194304;       // [1280][128][64] bf16 = 20 MB
    float* ML  = (float*)(Opart + 10485760);  // [1280][128] f32 = 0.66 MB

    hipLaunchKernelGGL(qkv_proj, dim3(768), dim3(256), 0, stream,
                       q, kv, Wq, bq, Wkv, bkv, QH, KH, VT);
    hipLaunchKernelGGL(attn_part, dim3(1280), dim3(256), 0, stream,
                       QH, KH, VT, Opart, ML);
    hipLaunchKernelGGL(attn_combine, dim3(512), dim3(256), 0, stream,
                       Opart, ML, YH);
    hipLaunchKernelGGL(out_proj, dim3(256), dim3(256), 0, stream, YH, Wp, bp, out);
}

// Round 12
// 107.247 us; speedup vs baseline: 1.0328x; 1.0328x over previous
//
#include <hip/hip_runtime.h>
#include <hip/hip_bf16.h>
#include <cmath>

typedef unsigned short u16;
typedef __attribute__((ext_vector_type(8))) short s8v;    // 8 x bf16 bits
typedef __attribute__((ext_vector_type(4))) float f4v;
typedef __attribute__((ext_vector_type(2))) float f2v;
typedef __attribute__((ext_vector_type(4))) unsigned int u32x4;
typedef __attribute__((ext_vector_type(4))) unsigned short u16x4;

#define MFMA(a,b,c) __builtin_amdgcn_mfma_f32_16x16x32_bf16((a),(b),(c),0,0,0)

__device__ __forceinline__ float bf2f(u16 u) {
    union { float f; unsigned i; } x; x.i = ((unsigned)u) << 16; return x.f;
}
__device__ __forceinline__ u16 f2bf(float f) {
    union { float f; unsigned i; } x; x.f = f;
    unsigned r = x.i + 0x7FFFu + ((x.i >> 16) & 1u);
    return (u16)(r >> 16);
}
__device__ __forceinline__ unsigned cvtpk(float lo, float hi) {
    unsigned r;
    asm("v_cvt_pk_bf16_f32 %0, %1, %2" : "=v"(r) : "v"(lo), "v"(hi));
    return r;
}
__device__ __forceinline__ void gload_lds16(const void* g, void* l) {
    __builtin_amdgcn_global_load_lds(
        (const __attribute__((address_space(1))) unsigned int*)g,
        (__attribute__((address_space(3))) unsigned int*)l, 16, 0, 0);
}
// swizzled byte offset into a [128 rows][128 B] LDS tile; bijective per row,
// write and read sides both conflict-free
__device__ __forceinline__ int swb(int row, int colb) {
    return row * 128 + (colb ^ ((((row >> 4) ^ row) & 7) << 4));
}

// chunks-per-qblock and per-p-tile prefix (512-key chunks, block-causal)
__constant__ int CPER[8]  = {1,1,2,2,3,3,4,4};
__constant__ int POFF[17] = {0,1,2,3,4,6,8,10,12,15,18,21,24,28,32,36,40};

// ---------------------------------------------------------------------------
// Kernel 1: fused QKV projection (f32 in -> bf16 MFMA -> bf16 out).
// Q output PRESCALED by 0.125*log2(e). Q,K: [b][h][T][d]; V: VT [b][h][d][T].
// XCD-chunked map; swizzled dbuf LDS; ONE barrier per k-step:
// window t = [write t+1 -> buf[(t+1)&1]; load t+2; MFMA buf[t&1]; barrier].
// ---------------------------------------------------------------------------
__global__ __launch_bounds__(256)
void qkv_proj(const float* __restrict__ q, const float* __restrict__ kv,
              const float* __restrict__ Wq, const float* __restrict__ bq,
              const float* __restrict__ Wkv, const float* __restrict__ bkv,
              u16* __restrict__ QH, u16* __restrict__ KH, u16* __restrict__ VT)
{
    __shared__ __align__(16) u16 Al[2][128 * 64];
    __shared__ __align__(16) u16 Bl[2][128 * 64];

    const int bid = blockIdx.x;
    const int x = bid & 7, i = bid >> 3;     // XCD-chunked: same-mt consecutive
    const int mt = x + 8 * (i / 12);
    const int nt = i % 12;
    const int m0 = mt << 7, n0 = nt << 7;

    const int tid  = threadIdx.x;
    const int lane = tid & 63;
    const int w    = tid >> 6;
    const int wr = (w >> 1) * 64, wc = (w & 1) * 64;
    const int cl = lane & 15, rl = lane >> 4;

    const int bb  = m0 >> 11;
    const int t0  = m0 & 2047;
    const int vv  = t0 >> 8;
    const int hw0 = t0 & 255;

    const float* Abase = ((nt < 4) ? q : kv) + (size_t)(vv * 4 + bb) * 131072 + hw0;

    const float* W; const float* bias; int NW, wn0, dn0; u16* dst;
    if (nt < 4)      { W = Wq;  bias = bq;  NW = 512;  wn0 = n0;       dn0 = n0;        dst = QH; }
    else if (nt < 8) { W = Wkv; bias = bkv; NW = 1024; wn0 = n0 - 512; dn0 = n0 - 512;  dst = KH; }
    else             { W = Wkv; bias = bkv; NW = 1024; wn0 = n0 - 512; dn0 = n0 - 1024; dst = VT; }

    const float oscale = (nt < 4) ? 0.18033688011f : 1.0f;  // 0.125*log2(e)

    f4v acc[4][4] = {};
    f2v la0[8], lb0[8], la1[8], lb1[8];   // two named staging sets

    const int mh = tid & 63;          // row pair: rows 2*mh, 2*mh+1
    const int kb = tid >> 6;          // k-oct within BK=32

#define QKV_LOAD(dA, dB, k0_) do {                                           \
        const float* gA = Abase + (size_t)((k0_) + kb * 8) * 256 + mh * 2;   \
        const float* gB = W + (size_t)((k0_) + kb * 8) * NW + wn0 + mh * 2;  \
        _Pragma("unroll")                                                    \
        for (int j = 0; j < 8; ++j) {                                        \
            dA[j] = *reinterpret_cast<const f2v*>(gA + j * 256);             \
            dB[j] = *reinterpret_cast<const f2v*>(gB + (size_t)j * NW);      \
        }                                                                    \
    } while (0)

#define QKV_WRITE(bufi, sA, sB) do {                                         \
        _Pragma("unroll")                                                    \
        for (int e = 0; e < 2; ++e) {                                        \
            u32x4 pa, pb;                                                    \
            _Pragma("unroll")                                                \
            for (int jj = 0; jj < 4; ++jj) {                                 \
                pa[jj] = cvtpk(sA[jj * 2][e], sA[jj * 2 + 1][e]);            \
                pb[jj] = cvtpk(sB[jj * 2][e], sB[jj * 2 + 1][e]);            \
            }                                                                \
            *(u32x4*)((char*)&Al[bufi][0] + swb(mh * 2 + e, kb * 16)) = pa;  \
            *(u32x4*)((char*)&Bl[bufi][0] + swb(mh * 2 + e, kb * 16)) = pb;  \
        }                                                                    \
    } while (0)

#define QKV_MFMA(bufi) do {                                                  \
        s8v af[4], bf[4];                                                    \
        _Pragma("unroll")                                                    \
        for (int mi = 0; mi < 4; ++mi)                                       \
            af[mi] = *(const s8v*)((const char*)&Al[bufi][0]                 \
                                   + swb(wr + mi * 16 + cl, rl * 16));       \
        _Pragma("unroll")                                                    \
        for (int ni = 0; ni < 4; ++ni)                                       \
            bf[ni] = *(const s8v*)((const char*)&Bl[bufi][0]                 \
                                   + swb(wc + ni * 16 + cl, rl * 16));       \
        _Pragma("unroll")                                                    \
        for (int mi = 0; mi < 4; ++mi)                                       \
            _Pragma("unroll")                                                \
            for (int ni = 0; ni < 4; ++ni)                                   \
                acc[mi][ni] = MFMA(af[mi], bf[ni], acc[mi][ni]);             \
    } while (0)

    // prologue: tile0 -> buf0; tile1 -> regs set1
    QKV_LOAD(la0, lb0, 0);
    QKV_WRITE(0, la0, lb0);
    QKV_LOAD(la1, lb1, 32);
    __syncthreads();

    #pragma unroll
    for (int it = 0; it < 8; ++it) {
        const int t = it * 2;
        // window t (even): write t+1 -> buf1, load t+2 -> set0, MFMA buf0
        QKV_WRITE(1, la1, lb1);
        if (t + 2 < 16) QKV_LOAD(la0, lb0, (t + 2) * 32);
        QKV_MFMA(0);
        __syncthreads();
        // window t+1 (odd): write t+2 -> buf0, load t+3 -> set1, MFMA buf1
        if (t + 2 < 16) QKV_WRITE(0, la0, lb0);
        if (t + 3 < 16) QKV_LOAD(la1, lb1, (t + 3) * 32);
        QKV_MFMA(1);
        __syncthreads();
    }
#undef QKV_LOAD
#undef QKV_WRITE
#undef QKV_MFMA

    if (nt < 8) {
        #pragma unroll
        for (int ni = 0; ni < 4; ++ni) {
            const int nl   = wc + ni * 16 + cl;
            const float bv = bias[wn0 + nl];
            const int cout = dn0 + nl;
            const int hh = cout >> 6, dd = cout & 63;
            const size_t obase = ((size_t)(bb * 8 + hh) * 2048) * 64 + dd;
            #pragma unroll
            for (int mi = 0; mi < 4; ++mi)
                #pragma unroll
                for (int r = 0; r < 4; ++r) {
                    const int m = m0 + wr + mi * 16 + rl * 4 + r;
                    const int t = m & 2047;
                    dst[obase + (size_t)t * 64] = f2bf((acc[mi][ni][r] + bv) * oscale);
                }
        }
    } else {
        #pragma unroll
        for (int ni = 0; ni < 4; ++ni) {
            const int nl   = wc + ni * 16 + cl;
            const float bv = bias[wn0 + nl];
            const int cout = dn0 + nl;
            const int hh = cout >> 6, dd = cout & 63;
            const size_t obase = ((size_t)(bb * 8 + hh) * 64 + dd) * 2048;
            #pragma unroll
            for (int mi = 0; mi < 4; ++mi) {
                const int m = m0 + wr + mi * 16 + rl * 4;
                const int t = m & 2047;
                u16x4 pk;
                #pragma unroll
                for (int r = 0; r < 4; ++r) pk[r] = f2bf(acc[mi][ni][r] + bv);
                *reinterpret_cast<u16x4*>(dst + obase + t) = pk;
            }
        }
    }
}

// ---------------------------------------------------------------------------
// Kernel 2a: attention partials. WG = (bh, 128-row q-tile p, 512-key chunk c).
// Fixed-max softmax; KVBLK=64; gload_lds with pre-swizzled source.
// ---------------------------------------------------------------------------
__global__ __launch_bounds__(256, 3)
void attn_part(const u16* __restrict__ QH, const u16* __restrict__ KH,
               const u16* __restrict__ VT,
               u16* __restrict__ Opart, float* __restrict__ ML)
{
    __shared__ __align__(16) u16 Kl[2][4096];  // [64 key][64 d], byte^=(key&7)<<4
    __shared__ __align__(16) u16 Vl[2][4096];  // [64 d][64 key], byte^=(d&7)<<4
    __shared__ u16 Pl[4][32][36];              // per-wave 32-key P slice

    const int wg = blockIdx.x;
    const int bh = wg & 31;
    const int s  = 39 - (wg >> 5);        // heavy (512-key) chunks first
    int p = 0;
    #pragma unroll
    for (int i = 0; i < 15; ++i) p += (s >= POFF[i + 1]) ? 1 : 0;
    const int c  = s - POFF[p];
    const int qb = p >> 1;
    const int kstart = c * 512;
    const int nk = min(512, (qb + 1) * 256 - kstart);
    const int nt64 = nk >> 6;             // 4 or 8 key tiles of 64

    const int tid = threadIdx.x, lane = tid & 63, w = tid >> 6;
    const int cl = lane & 15, rl = lane >> 4;

    const u16* Qb = QH + (size_t)bh * 131072;
    const u16* Kb = KH + (size_t)bh * 131072;
    const u16* Vb = VT + (size_t)bh * 131072;

    const int qrow0 = p * 128 + w * 32;

    s8v qf[2][2];
    #pragma unroll
    for (int mi = 0; mi < 2; ++mi)
        #pragma unroll
        for (int kf = 0; kf < 2; ++kf)
            qf[mi][kf] = *reinterpret_cast<const s8v*>(
                Qb + (size_t)(qrow0 + mi * 16 + cl) * 64 + kf * 32 + rl * 8);

    // per-thread pre-swizzled source offsets (slot f = w*128 + i*64 + lane)
    unsigned kofs[2], vofs[2];
    #pragma unroll
    for (int i = 0; i < 2; ++i) {
        const int f = w * 128 + i * 64 + lane;
        const int row = f >> 3;
        kofs[i] = row * 128 + (((f & 7) * 16) ^ ((row & 7) << 4));
        vofs[i] = row * 4096 + (((f & 7) * 16) ^ ((row & 7) << 4));
    }

#define ISSUE(bufi, kb0_) do {                                               \
        const char* kG = (const char*)Kb + (size_t)(kb0_) * 128;             \
        const char* vG = (const char*)Vb + (size_t)(kb0_) * 2;               \
        char* kL = (char*)&Kl[bufi][0] + w * 2048;                           \
        char* vL = (char*)&Vl[bufi][0] + w * 2048;                           \
        _Pragma("unroll")                                                    \
        for (int i_ = 0; i_ < 2; ++i_) {                                     \
            gload_lds16(kG + kofs[i_], kL + i_ * 1024);                      \
            gload_lds16(vG + vofs[i_], vL + i_ * 1024);                      \
        }                                                                    \
    } while (0)

    f4v o[2][4] = {};
    float lp[8] = {0.f, 0.f, 0.f, 0.f, 0.f, 0.f, 0.f, 0.f};

    ISSUE(0, kstart);

    for (int kt = 0; kt < nt64; ++kt) {
        asm volatile("s_waitcnt vmcnt(0)" ::: "memory");
        __builtin_amdgcn_sched_barrier(0);
        __syncthreads();
        if (kt + 1 < nt64) ISSUE((kt + 1) & 1, kstart + (kt + 1) * 64);

        const char* Kbase = (const char*)&Kl[kt & 1][0];
        const char* Vbase = (const char*)&Vl[kt & 1][0];

        // S = Q K^T (swizzled LDS reads)
        f4v sc[2][4] = {};
        #pragma unroll
        for (int ni = 0; ni < 4; ++ni)
            #pragma unroll
            for (int kf = 0; kf < 2; ++kf) {
                const int row = ni * 16 + cl;
                s8v kfr = *reinterpret_cast<const s8v*>(
                    Kbase + row * 128 + ((kf * 64 + rl * 16) ^ ((row & 7) << 4)));
                sc[0][ni] = MFMA(qf[0][kf], kfr, sc[0][ni]);
                sc[1][ni] = MFMA(qf[1][kf], kfr, sc[1][ni]);
            }

        // fixed-max softmax: P = exp2(s) directly (s bounded, Q prescaled)
        #pragma unroll
        for (int mi = 0; mi < 2; ++mi)
            #pragma unroll
            for (int ni = 0; ni < 4; ++ni)
                #pragma unroll
                for (int r = 0; r < 4; ++r)
                    sc[mi][ni][r] = exp2f(sc[mi][ni][r]);
        #pragma unroll
        for (int mi = 0; mi < 2; ++mi)
            #pragma unroll
            for (int r = 0; r < 4; ++r)
                lp[mi * 4 + r] += sc[mi][0][r] + sc[mi][1][r]
                                + sc[mi][2][r] + sc[mi][3][r];

        // PV in two 32-key windows through per-wave LDS
        #pragma unroll
        for (int kw = 0; kw < 2; ++kw) {
            #pragma unroll
            for (int mi = 0; mi < 2; ++mi)
                #pragma unroll
                for (int jj = 0; jj < 2; ++jj) {
                    const int ni = kw * 2 + jj;
                    const unsigned w0 = cvtpk(sc[mi][ni][0], sc[mi][ni][1]);
                    const unsigned w1 = cvtpk(sc[mi][ni][2], sc[mi][ni][3]);
                    const int col = jj * 16 + cl;
                    Pl[w][mi * 16 + rl * 4 + 0][col] = (u16)w0;
                    Pl[w][mi * 16 + rl * 4 + 1][col] = (u16)(w0 >> 16);
                    Pl[w][mi * 16 + rl * 4 + 2][col] = (u16)w1;
                    Pl[w][mi * 16 + rl * 4 + 3][col] = (u16)(w1 >> 16);
                }
            s8v pf0 = *reinterpret_cast<const s8v*>(&Pl[w][cl][rl * 8]);
            s8v pf1 = *reinterpret_cast<const s8v*>(&Pl[w][16 + cl][rl * 8]);
            #pragma unroll
            for (int di = 0; di < 4; ++di) {
                const int row = di * 16 + cl;
                s8v vf = *reinterpret_cast<const s8v*>(
                    Vbase + row * 128 + ((kw * 64 + rl * 16) ^ ((row & 7) << 4)));
                o[0][di] = MFMA(pf0, vf, o[0][di]);
                o[1][di] = MFMA(pf1, vf, o[1][di]);
            }
        }
    }
#undef ISSUE

    // write partial: Ohat = O/l (bf16), l (f32)
    const int slot = bh * 40 + POFF[p] + c;
    #pragma unroll
    for (int mi = 0; mi < 2; ++mi)
        #pragma unroll
        for (int r = 0; r < 4; ++r) {
            const int idx = mi * 4 + r;
            float ls = lp[idx];
            ls += __shfl_xor(ls, 1);
            ls += __shfl_xor(ls, 2);
            ls += __shfl_xor(ls, 4);
            ls += __shfl_xor(ls, 8);
            const float inv = 1.f / ls;
            const int rloc = w * 32 + mi * 16 + rl * 4 + r;
            if (cl == 0) ML[(size_t)slot * 128 + rloc] = ls;
            #pragma unroll
            for (int di = 0; di < 4; ++di)
                Opart[(size_t)slot * 8192 + rloc * 64 + di * 16 + cl] =
                    f2bf(o[mi][di][r] * inv);
        }
}

// ---------------------------------------------------------------------------
// Kernel 2b: combine partials -> YH [b][t][c] bf16. weights = l_c / sum l_c.
// ---------------------------------------------------------------------------
__global__ __launch_bounds__(256)
void attn_combine(const u16* __restrict__ Opart, const float* __restrict__ ML,
                  u16* __restrict__ YH)
{
    const int wg = blockIdx.x;
    const int bh = wg & 31;
    const int p  = wg >> 5;
    const int b = bh >> 3, h = bh & 7;
    const int nc = CPER[p >> 1];
    const int sb = bh * 40 + POFF[p];

    const int t = threadIdx.x;
    const int rloc = t >> 1;
    const int dh = (t & 1) * 32;

    float lc[4], L = 0.f;
    for (int c = 0; c < nc; ++c) {
        lc[c] = ML[(size_t)(sb + c) * 128 + rloc];
        L += lc[c];
    }
    const float invL = 1.f / L;
    float wgt[4];
    for (int c = 0; c < nc; ++c) wgt[c] = lc[c] * invL;

    f4v a[8] = {};
    for (int c = 0; c < nc; ++c) {
        const float wv = wgt[c];
        #pragma unroll
        for (int u = 0; u < 4; ++u) {
            s8v vv = *reinterpret_cast<const s8v*>(
                &Opart[(size_t)(sb + c) * 8192 + rloc * 64 + dh + u * 8]);
            #pragma unroll
            for (int e = 0; e < 4; ++e) a[u * 2][e]     += wv * bf2f((u16)vv[e]);
            #pragma unroll
            for (int e = 0; e < 4; ++e) a[u * 2 + 1][e] += wv * bf2f((u16)vv[e + 4]);
        }
    }

    const size_t ybase = ((size_t)b * 2048 + p * 128 + rloc) * 512 + h * 64 + dh;
    #pragma unroll
    for (int u = 0; u < 4; ++u) {
        s8v ov;
        #pragma unroll
        for (int e = 0; e < 4; ++e) ov[e]     = (short)f2bf(a[u * 2][e]);
        #pragma unroll
        for (int e = 0; e < 4; ++e) ov[e + 4] = (short)f2bf(a[u * 2 + 1][e]);
        *reinterpret_cast<s8v*>(YH + ybase + u * 8) = ov;
    }
}

// ---------------------------------------------------------------------------
// Kernel 3: output projection (transposed): C'[c][tok] = Wp^T . Y^T.
// Same single-barrier dbuf pipeline as qkv_proj.
// ---------------------------------------------------------------------------
__global__ __launch_bounds__(256)
void out_proj(const u16* __restrict__ YH, const float* __restrict__ Wp,
              const float* __restrict__ bp, float* __restrict__ out)
{
    __shared__ __align__(16) u16 Al[2][128 * 64];   // Wp^T tiles, swizzled
    __shared__ u16 Bl[2][128][40];                  // Y tiles

    const int bid = blockIdx.x;
    const int x = bid & 7, i = bid >> 3;            // 256 blocks
    const int mt = x + 8 * (i >> 2);
    const int ct = i & 3;
    const int c0 = ct << 7, m0 = mt << 7;

    const int tid = threadIdx.x, lane = tid & 63, w = tid >> 6;
    const int wr = (w >> 1) * 64, wc = (w & 1) * 64;
    const int cl = lane & 15, rl = lane >> 4;

    f4v acc[4][4] = {};
    f2v wa0[8], wa1[8];
    s8v sy0[2], sy1[2];

    const int mh = tid & 63;          // cout pair: rows 2*mh, 2*mh+1
    const int kb = tid >> 6;          // k-oct
    const int br = tid >> 2;
    const int bq4 = (tid & 3) * 8;

#define OP_LOAD(dA, dY, k0_) do {                                            \
        const float* gA = Wp + (size_t)((k0_) + kb * 8) * 512 + c0 + mh * 2; \
        _Pragma("unroll")                                                    \
        for (int j = 0; j < 8; ++j)                                          \
            dA[j] = *reinterpret_cast<const f2v*>(gA + j * 512);             \
        _Pragma("unroll")                                                    \
        for (int it = 0; it < 2; ++it)                                       \
            dY[it] = *reinterpret_cast<const s8v*>(                          \
                YH + (size_t)(m0 + br + it * 64) * 512 + (k0_) + bq4);       \
    } while (0)

#define OP_WRITE(bufi, sA, sY) do {                                          \
        _Pragma("unroll")                                                    \
        for (int e = 0; e < 2; ++e) {                                        \
            u32x4 pa;                                                        \
            _Pragma("unroll")                                                \
            for (int jj = 0; jj < 4; ++jj)                                   \
                pa[jj] = cvtpk(sA[jj * 2][e], sA[jj * 2 + 1][e]);            \
            *(u32x4*)((char*)&Al[bufi][0] + swb(mh * 2 + e, kb * 16)) = pa;  \
        }                                                                    \
        _Pragma("unroll")                                                    \
        for (int it = 0; it < 2; ++it)                                       \
            *reinterpret_cast<s8v*>(&Bl[bufi][br + it * 64][bq4]) = sY[it];  \
    } while (0)

#define OP_MFMA(bufi) do {                                                   \
        s8v af[4], bfr[4];                                                   \
        _Pragma("unroll")                                                    \
        for (int mi = 0; mi < 4; ++mi)                                       \
            af[mi] = *(const s8v*)((const char*)&Al[bufi][0]                 \
                                   + swb(wr + mi * 16 + cl, rl * 16));       \
        _Pragma("unroll")                                                    \
        for (int ni = 0; ni < 4; ++ni)                                       \
            bfr[ni] = *reinterpret_cast<const s8v*>(                         \
                &Bl[bufi][wc + ni * 16 + cl][rl * 8]);                       \
        _Pragma("unroll")                                                    \
        for (int mi = 0; mi < 4; ++mi)                                       \
            _Pragma("unroll")                                                \
            for (int ni = 0; ni < 4; ++ni)                                   \
                acc[mi][ni] = MFMA(af[mi], bfr[ni], acc[mi][ni]);            \
    } while (0)

    OP_LOAD(wa0, sy0, 0);
    OP_WRITE(0, wa0, sy0);
    OP_LOAD(wa1, sy1, 32);
    __syncthreads();

    #pragma unroll
    for (int it = 0; it < 8; ++it) {
        const int t = it * 2;
        OP_WRITE(1, wa1, sy1);
        if (t + 2 < 16) OP_LOAD(wa0, sy0, (t + 2) * 32);
        OP_MFMA(0);
        __syncthreads();
        if (t + 2 < 16) OP_WRITE(0, wa0, sy0);
        if (t + 3 < 16) OP_LOAD(wa1, sy1, (t + 3) * 32);
        OP_MFMA(1);
        __syncthreads();
    }
#undef OP_LOAD
#undef OP_WRITE
#undef OP_MFMA

    #pragma unroll
    for (int mi = 0; mi < 4; ++mi)
        #pragma unroll
        for (int r = 0; r < 4; ++r) {
            const int c = c0 + wr + mi * 16 + rl * 4 + r;   // D row = cout
            const float bv = bp[c];
            #pragma unroll
            for (int ni = 0; ni < 4; ++ni) {
                const int tok = m0 + wc + ni * 16 + cl;     // D col = token
                const int bb = tok >> 11, t = tok & 2047;
                const int vv = t >> 8, hw = t & 255;
                out[(size_t)(vv * 4 + bb) * 131072 + (size_t)c * 256 + hw] =
                    acc[mi][ni][r] + bv;
            }
        }
}

// ---------------------------------------------------------------------------
extern "C" void kernel_launch(void* const* d_in, const int* in_sizes, int n_in,
                              void* d_out, int out_size, void* d_ws, size_t ws_size,
                              hipStream_t stream)
{
    const float* q   = (const float*)d_in[0];
    const float* kv  = (const float*)d_in[1];
    const float* Wq  = (const float*)d_in[2];
    const float* bq  = (const float*)d_in[3];
    const float* Wkv = (const float*)d_in[4];
    const float* bkv = (const float*)d_in[5];
    const float* Wp  = (const float*)d_in[6];
    const float* bp  = (const float*)d_in[7];
    float* out = (float*)d_out;

    u16* ws = (u16*)d_ws;
    u16* QH = ws;                    // [4][8][2048][64] bf16, prescaled Q
    u16* KH = QH + 4194304;          // [4][8][2048][64]
    u16* VT = KH + 4194304;          // [4][8][64][2048]
    u16* YH = VT + 4194304;          // [4][2048][512]
    u16* Opart = YH + 4194304;       // [1280][128][64] bf16 = 20 MB
    float* ML  = (float*)(Opart + 10485760);  // [1280][128] f32 = 0.66 MB

    hipLaunchKernelGGL(qkv_proj, dim3(768), dim3(256), 0, stream,
                       q, kv, Wq, bq, Wkv, bkv, QH, KH, VT);
    hipLaunchKernelGGL(attn_part, dim3(1280), dim3(256), 0, stream,
                       QH, KH, VT, Opart, ML);
    hipLaunchKernelGGL(attn_combine, dim3(512), dim3(256), 0, stream,
                       Opart, ML, YH);
    hipLaunchKernelGGL(out_proj, dim3(256), dim3(256), 0, stream, YH, Wp, bp, out);
}

// Round 13
// 103.820 us; speedup vs baseline: 1.0669x; 1.0330x over previous
//
#include <hip/hip_runtime.h>
#include <hip/hip_bf16.h>
#include <cmath>

typedef unsigned short u16;
typedef __attribute__((ext_vector_type(8))) short s8v;    // 8 x bf16 bits
typedef __attribute__((ext_vector_type(4))) float f4v;
typedef __attribute__((ext_vector_type(2))) float f2v;
typedef __attribute__((ext_vector_type(4))) unsigned int u32x4;
typedef __attribute__((ext_vector_type(4))) unsigned short u16x4;

#define MFMA(a,b,c) __builtin_amdgcn_mfma_f32_16x16x32_bf16((a),(b),(c),0,0,0)

__device__ __forceinline__ float bf2f(u16 u) {
    union { float f; unsigned i; } x; x.i = ((unsigned)u) << 16; return x.f;
}
__device__ __forceinline__ u16 f2bf(float f) {
    union { float f; unsigned i; } x; x.f = f;
    unsigned r = x.i + 0x7FFFu + ((x.i >> 16) & 1u);
    return (u16)(r >> 16);
}
__device__ __forceinline__ unsigned cvtpk(float lo, float hi) {
    unsigned r;
    asm("v_cvt_pk_bf16_f32 %0, %1, %2" : "=v"(r) : "v"(lo), "v"(hi));
    return r;
}
__device__ __forceinline__ void gload_lds16(const void* g, void* l) {
    __builtin_amdgcn_global_load_lds(
        (const __attribute__((address_space(1))) unsigned int*)g,
        (__attribute__((address_space(3))) unsigned int*)l, 16, 0, 0);
}
// swizzled byte offset into a [128 rows][128 B] LDS tile; bijective per row,
// write and read sides both conflict-free (b128 minimum aliasing)
__device__ __forceinline__ int swb(int row, int colb) {
    return row * 128 + (colb ^ ((((row >> 4) ^ row) & 7) << 4));
}

// chunks-per-qblock and per-p-tile prefix (512-key chunks, block-causal)
__constant__ int CPER[8]  = {1,1,2,2,3,3,4,4};
__constant__ int POFF[17] = {0,1,2,3,4,6,8,10,12,15,18,21,24,28,32,36,40};

// ---------------------------------------------------------------------------
// Kernel 1: fused QKV projection (f32 in -> bf16 MFMA -> bf16 out).
// Q output PRESCALED by 0.125*log2(e). Q,K: [b][h][T][d]; V: VT [b][h][d][T].
// A and B tiles MERGED into one [2][128][128B] LDS buffer (A colb 0-63,
// B colb 64-127; per-row XOR is bijective so images stay disjoint).
// LDS 32KB -> 3 grid-blocks/CU all resident -> TLP covers barrier drains.
// ---------------------------------------------------------------------------
__global__ __launch_bounds__(256, 3)
void qkv_proj(const float* __restrict__ q, const float* __restrict__ kv,
              const float* __restrict__ Wq, const float* __restrict__ bq,
              const float* __restrict__ Wkv, const float* __restrict__ bkv,
              u16* __restrict__ QH, u16* __restrict__ KH, u16* __restrict__ VT)
{
    __shared__ __align__(16) u16 Tl[2][128 * 64];   // A+B merged, 16KB/tile

    const int bid = blockIdx.x;
    const int x = bid & 7, i = bid >> 3;     // XCD-chunked: same-mt consecutive
    const int mt = x + 8 * (i / 12);
    const int nt = i % 12;
    const int m0 = mt << 7, n0 = nt << 7;

    const int tid  = threadIdx.x;
    const int lane = tid & 63;
    const int w    = tid >> 6;
    const int wr = (w >> 1) * 64, wc = (w & 1) * 64;
    const int cl = lane & 15, rl = lane >> 4;

    const int bb  = m0 >> 11;
    const int t0  = m0 & 2047;
    const int vv  = t0 >> 8;
    const int hw0 = t0 & 255;

    const float* Abase = ((nt < 4) ? q : kv) + (size_t)(vv * 4 + bb) * 131072 + hw0;

    const float* W; const float* bias; int NW, wn0, dn0; u16* dst;
    if (nt < 4)      { W = Wq;  bias = bq;  NW = 512;  wn0 = n0;       dn0 = n0;        dst = QH; }
    else if (nt < 8) { W = Wkv; bias = bkv; NW = 1024; wn0 = n0 - 512; dn0 = n0 - 512;  dst = KH; }
    else             { W = Wkv; bias = bkv; NW = 1024; wn0 = n0 - 512; dn0 = n0 - 1024; dst = VT; }

    const float oscale = (nt < 4) ? 0.18033688011f : 1.0f;  // 0.125*log2(e)

    f4v acc[4][4] = {};
    f2v la0[8], lb0[8], la1[8], lb1[8];   // two named staging sets

    const int mh = tid & 63;          // row pair: rows 2*mh, 2*mh+1
    const int kb = tid >> 6;          // k-oct within BK=32

#define QKV_LOAD(dA, dB, k0_) do {                                           \
        const float* gA = Abase + (size_t)((k0_) + kb * 8) * 256 + mh * 2;   \
        const float* gB = W + (size_t)((k0_) + kb * 8) * NW + wn0 + mh * 2;  \
        _Pragma("unroll")                                                    \
        for (int j = 0; j < 8; ++j) {                                        \
            dA[j] = *reinterpret_cast<const f2v*>(gA + j * 256);             \
            dB[j] = *reinterpret_cast<const f2v*>(gB + (size_t)j * NW);      \
        }                                                                    \
    } while (0)

#define QKV_WRITE(bufi, sA, sB) do {                                         \
        _Pragma("unroll")                                                    \
        for (int e = 0; e < 2; ++e) {                                        \
            u32x4 pa, pb;                                                    \
            _Pragma("unroll")                                                \
            for (int jj = 0; jj < 4; ++jj) {                                 \
                pa[jj] = cvtpk(sA[jj * 2][e], sA[jj * 2 + 1][e]);            \
                pb[jj] = cvtpk(sB[jj * 2][e], sB[jj * 2 + 1][e]);            \
            }                                                                \
            *(u32x4*)((char*)&Tl[bufi][0] + swb(mh * 2 + e, kb * 16)) = pa;  \
            *(u32x4*)((char*)&Tl[bufi][0] + swb(mh * 2 + e, 64 + kb * 16)) = pb; \
        }                                                                    \
    } while (0)

#define QKV_MFMA(bufi) do {                                                  \
        s8v af[4], bf[4];                                                    \
        _Pragma("unroll")                                                    \
        for (int mi = 0; mi < 4; ++mi)                                       \
            af[mi] = *(const s8v*)((const char*)&Tl[bufi][0]                 \
                                   + swb(wr + mi * 16 + cl, rl * 16));       \
        _Pragma("unroll")                                                    \
        for (int ni = 0; ni < 4; ++ni)                                       \
            bf[ni] = *(const s8v*)((const char*)&Tl[bufi][0]                 \
                                   + swb(wc + ni * 16 + cl, 64 + rl * 16));  \
        _Pragma("unroll")                                                    \
        for (int mi = 0; mi < 4; ++mi)                                       \
            _Pragma("unroll")                                                \
            for (int ni = 0; ni < 4; ++ni)                                   \
                acc[mi][ni] = MFMA(af[mi], bf[ni], acc[mi][ni]);             \
    } while (0)

    // prologue: tile0 -> buf0; tile1 -> regs set1
    QKV_LOAD(la0, lb0, 0);
    QKV_WRITE(0, la0, lb0);
    QKV_LOAD(la1, lb1, 32);
    __syncthreads();

    #pragma unroll
    for (int it = 0; it < 8; ++it) {
        const int t = it * 2;
        // window t (even): write t+1 -> buf1, load t+2 -> set0, MFMA buf0
        QKV_WRITE(1, la1, lb1);
        if (t + 2 < 16) QKV_LOAD(la0, lb0, (t + 2) * 32);
        QKV_MFMA(0);
        __syncthreads();
        // window t+1 (odd): write t+2 -> buf0, load t+3 -> set1, MFMA buf1
        if (t + 2 < 16) QKV_WRITE(0, la0, lb0);
        if (t + 3 < 16) QKV_LOAD(la1, lb1, (t + 3) * 32);
        QKV_MFMA(1);
        __syncthreads();
    }
#undef QKV_LOAD
#undef QKV_WRITE
#undef QKV_MFMA

    if (nt < 8) {
        #pragma unroll
        for (int ni = 0; ni < 4; ++ni) {
            const int nl   = wc + ni * 16 + cl;
            const float bv = bias[wn0 + nl];
            const int cout = dn0 + nl;
            const int hh = cout >> 6, dd = cout & 63;
            const size_t obase = ((size_t)(bb * 8 + hh) * 2048) * 64 + dd;
            #pragma unroll
            for (int mi = 0; mi < 4; ++mi)
                #pragma unroll
                for (int r = 0; r < 4; ++r) {
                    const int m = m0 + wr + mi * 16 + rl * 4 + r;
                    const int t = m & 2047;
                    dst[obase + (size_t)t * 64] = f2bf((acc[mi][ni][r] + bv) * oscale);
                }
        }
    } else {
        #pragma unroll
        for (int ni = 0; ni < 4; ++ni) {
            const int nl   = wc + ni * 16 + cl;
            const float bv = bias[wn0 + nl];
            const int cout = dn0 + nl;
            const int hh = cout >> 6, dd = cout & 63;
            const size_t obase = ((size_t)(bb * 8 + hh) * 64 + dd) * 2048;
            #pragma unroll
            for (int mi = 0; mi < 4; ++mi) {
                const int m = m0 + wr + mi * 16 + rl * 4;
                const int t = m & 2047;
                u16x4 pk;
                #pragma unroll
                for (int r = 0; r < 4; ++r) pk[r] = f2bf(acc[mi][ni][r] + bv);
                *reinterpret_cast<u16x4*>(dst + obase + t) = pk;
            }
        }
    }
}

// ---------------------------------------------------------------------------
// Kernel 2a: attention partials. WG = (bh, 128-row q-tile p, 512-key chunk c).
// Fixed-max softmax; KVBLK=64; gload_lds with pre-swizzled source.
// ---------------------------------------------------------------------------
__global__ __launch_bounds__(256, 3)
void attn_part(const u16* __restrict__ QH, const u16* __restrict__ KH,
               const u16* __restrict__ VT,
               u16* __restrict__ Opart, float* __restrict__ ML)
{
    __shared__ __align__(16) u16 Kl[2][4096];  // [64 key][64 d], byte^=(key&7)<<4
    __shared__ __align__(16) u16 Vl[2][4096];  // [64 d][64 key], byte^=(d&7)<<4
    __shared__ u16 Pl[4][32][36];              // per-wave 32-key P slice

    const int wg = blockIdx.x;
    const int bh = wg & 31;
    const int s  = 39 - (wg >> 5);        // heavy (512-key) chunks first
    int p = 0;
    #pragma unroll
    for (int i = 0; i < 15; ++i) p += (s >= POFF[i + 1]) ? 1 : 0;
    const int c  = s - POFF[p];
    const int qb = p >> 1;
    const int kstart = c * 512;
    const int nk = min(512, (qb + 1) * 256 - kstart);
    const int nt64 = nk >> 6;             // 4 or 8 key tiles of 64

    const int tid = threadIdx.x, lane = tid & 63, w = tid >> 6;
    const int cl = lane & 15, rl = lane >> 4;

    const u16* Qb = QH + (size_t)bh * 131072;
    const u16* Kb = KH + (size_t)bh * 131072;
    const u16* Vb = VT + (size_t)bh * 131072;

    const int qrow0 = p * 128 + w * 32;

    s8v qf[2][2];
    #pragma unroll
    for (int mi = 0; mi < 2; ++mi)
        #pragma unroll
        for (int kf = 0; kf < 2; ++kf)
            qf[mi][kf] = *reinterpret_cast<const s8v*>(
                Qb + (size_t)(qrow0 + mi * 16 + cl) * 64 + kf * 32 + rl * 8);

    // per-thread pre-swizzled source offsets (slot f = w*128 + i*64 + lane)
    unsigned kofs[2], vofs[2];
    #pragma unroll
    for (int i = 0; i < 2; ++i) {
        const int f = w * 128 + i * 64 + lane;
        const int row = f >> 3;
        kofs[i] = row * 128 + (((f & 7) * 16) ^ ((row & 7) << 4));
        vofs[i] = row * 4096 + (((f & 7) * 16) ^ ((row & 7) << 4));
    }

#define ISSUE(bufi, kb0_) do {                                               \
        const char* kG = (const char*)Kb + (size_t)(kb0_) * 128;             \
        const char* vG = (const char*)Vb + (size_t)(kb0_) * 2;               \
        char* kL = (char*)&Kl[bufi][0] + w * 2048;                           \
        char* vL = (char*)&Vl[bufi][0] + w * 2048;                           \
        _Pragma("unroll")                                                    \
        for (int i_ = 0; i_ < 2; ++i_) {                                     \
            gload_lds16(kG + kofs[i_], kL + i_ * 1024);                      \
            gload_lds16(vG + vofs[i_], vL + i_ * 1024);                      \
        }                                                                    \
    } while (0)

    f4v o[2][4] = {};
    float lp[8] = {0.f, 0.f, 0.f, 0.f, 0.f, 0.f, 0.f, 0.f};

    ISSUE(0, kstart);

    for (int kt = 0; kt < nt64; ++kt) {
        asm volatile("s_waitcnt vmcnt(0)" ::: "memory");
        __builtin_amdgcn_sched_barrier(0);
        __syncthreads();
        if (kt + 1 < nt64) ISSUE((kt + 1) & 1, kstart + (kt + 1) * 64);

        const char* Kbase = (const char*)&Kl[kt & 1][0];
        const char* Vbase = (const char*)&Vl[kt & 1][0];

        // S = Q K^T (swizzled LDS reads)
        f4v sc[2][4] = {};
        #pragma unroll
        for (int ni = 0; ni < 4; ++ni)
            #pragma unroll
            for (int kf = 0; kf < 2; ++kf) {
                const int row = ni * 16 + cl;
                s8v kfr = *reinterpret_cast<const s8v*>(
                    Kbase + row * 128 + ((kf * 64 + rl * 16) ^ ((row & 7) << 4)));
                sc[0][ni] = MFMA(qf[0][kf], kfr, sc[0][ni]);
                sc[1][ni] = MFMA(qf[1][kf], kfr, sc[1][ni]);
            }

        // fixed-max softmax: P = exp2(s) directly (s bounded, Q prescaled)
        #pragma unroll
        for (int mi = 0; mi < 2; ++mi)
            #pragma unroll
            for (int ni = 0; ni < 4; ++ni)
                #pragma unroll
                for (int r = 0; r < 4; ++r)
                    sc[mi][ni][r] = exp2f(sc[mi][ni][r]);
        #pragma unroll
        for (int mi = 0; mi < 2; ++mi)
            #pragma unroll
            for (int r = 0; r < 4; ++r)
                lp[mi * 4 + r] += sc[mi][0][r] + sc[mi][1][r]
                                + sc[mi][2][r] + sc[mi][3][r];

        // PV in two 32-key windows through per-wave LDS
        #pragma unroll
        for (int kw = 0; kw < 2; ++kw) {
            #pragma unroll
            for (int mi = 0; mi < 2; ++mi)
                #pragma unroll
                for (int jj = 0; jj < 2; ++jj) {
                    const int ni = kw * 2 + jj;
                    const unsigned w0 = cvtpk(sc[mi][ni][0], sc[mi][ni][1]);
                    const unsigned w1 = cvtpk(sc[mi][ni][2], sc[mi][ni][3]);
                    const int col = jj * 16 + cl;
                    Pl[w][mi * 16 + rl * 4 + 0][col] = (u16)w0;
                    Pl[w][mi * 16 + rl * 4 + 1][col] = (u16)(w0 >> 16);
                    Pl[w][mi * 16 + rl * 4 + 2][col] = (u16)w1;
                    Pl[w][mi * 16 + rl * 4 + 3][col] = (u16)(w1 >> 16);
                }
            s8v pf0 = *reinterpret_cast<const s8v*>(&Pl[w][cl][rl * 8]);
            s8v pf1 = *reinterpret_cast<const s8v*>(&Pl[w][16 + cl][rl * 8]);
            #pragma unroll
            for (int di = 0; di < 4; ++di) {
                const int row = di * 16 + cl;
                s8v vf = *reinterpret_cast<const s8v*>(
                    Vbase + row * 128 + ((kw * 64 + rl * 16) ^ ((row & 7) << 4)));
                o[0][di] = MFMA(pf0, vf, o[0][di]);
                o[1][di] = MFMA(pf1, vf, o[1][di]);
            }
        }
    }
#undef ISSUE

    // write partial: Ohat = O/l (bf16), l (f32)
    const int slot = bh * 40 + POFF[p] + c;
    #pragma unroll
    for (int mi = 0; mi < 2; ++mi)
        #pragma unroll
        for (int r = 0; r < 4; ++r) {
            const int idx = mi * 4 + r;
            float ls = lp[idx];
            ls += __shfl_xor(ls, 1);
            ls += __shfl_xor(ls, 2);
            ls += __shfl_xor(ls, 4);
            ls += __shfl_xor(ls, 8);
            const float inv = 1.f / ls;
            const int rloc = w * 32 + mi * 16 + rl * 4 + r;
            if (cl == 0) ML[(size_t)slot * 128 + rloc] = ls;
            #pragma unroll
            for (int di = 0; di < 4; ++di)
                Opart[(size_t)slot * 8192 + rloc * 64 + di * 16 + cl] =
                    f2bf(o[mi][di][r] * inv);
        }
}

// ---------------------------------------------------------------------------
// Kernel 2b: combine partials -> YH [b][t][c] bf16. weights = l_c / sum l_c.
// ---------------------------------------------------------------------------
__global__ __launch_bounds__(256)
void attn_combine(const u16* __restrict__ Opart, const float* __restrict__ ML,
                  u16* __restrict__ YH)
{
    const int wg = blockIdx.x;
    const int bh = wg & 31;
    const int p  = wg >> 5;
    const int b = bh >> 3, h = bh & 7;
    const int nc = CPER[p >> 1];
    const int sb = bh * 40 + POFF[p];

    const int t = threadIdx.x;
    const int rloc = t >> 1;
    const int dh = (t & 1) * 32;

    float lc[4], L = 0.f;
    for (int c = 0; c < nc; ++c) {
        lc[c] = ML[(size_t)(sb + c) * 128 + rloc];
        L += lc[c];
    }
    const float invL = 1.f / L;
    float wgt[4];
    for (int c = 0; c < nc; ++c) wgt[c] = lc[c] * invL;

    f4v a[8] = {};
    for (int c = 0; c < nc; ++c) {
        const float wv = wgt[c];
        #pragma unroll
        for (int u = 0; u < 4; ++u) {
            s8v vv = *reinterpret_cast<const s8v*>(
                &Opart[(size_t)(sb + c) * 8192 + rloc * 64 + dh + u * 8]);
            #pragma unroll
            for (int e = 0; e < 4; ++e) a[u * 2][e]     += wv * bf2f((u16)vv[e]);
            #pragma unroll
            for (int e = 0; e < 4; ++e) a[u * 2 + 1][e] += wv * bf2f((u16)vv[e + 4]);
        }
    }

    const size_t ybase = ((size_t)b * 2048 + p * 128 + rloc) * 512 + h * 64 + dh;
    #pragma unroll
    for (int u = 0; u < 4; ++u) {
        s8v ov;
        #pragma unroll
        for (int e = 0; e < 4; ++e) ov[e]     = (short)f2bf(a[u * 2][e]);
        #pragma unroll
        for (int e = 0; e < 4; ++e) ov[e + 4] = (short)f2bf(a[u * 2 + 1][e]);
        *reinterpret_cast<s8v*>(YH + ybase + u * 8) = ov;
    }
}

// ---------------------------------------------------------------------------
// Kernel 3: output projection (transposed): C'[c][tok] = Wp^T . Y^T.
// Single-barrier dbuf pipeline.
// ---------------------------------------------------------------------------
__global__ __launch_bounds__(256)
void out_proj(const u16* __restrict__ YH, const float* __restrict__ Wp,
              const float* __restrict__ bp, float* __restrict__ out)
{
    __shared__ __align__(16) u16 Al[2][128 * 64];   // Wp^T tiles, swizzled
    __shared__ u16 Bl[2][128][40];                  // Y tiles

    const int bid = blockIdx.x;
    const int x = bid & 7, i = bid >> 3;            // 256 blocks
    const int mt = x + 8 * (i >> 2);
    const int ct = i & 3;
    const int c0 = ct << 7, m0 = mt << 7;

    const int tid = threadIdx.x, lane = tid & 63, w = tid >> 6;
    const int wr = (w >> 1) * 64, wc = (w & 1) * 64;
    const int cl = lane & 15, rl = lane >> 4;

    f4v acc[4][4] = {};
    f2v wa0[8], wa1[8];
    s8v sy0[2], sy1[2];

    const int mh = tid & 63;          // cout pair: rows 2*mh, 2*mh+1
    const int kb = tid >> 6;          // k-oct
    const int br = tid >> 2;
    const int bq4 = (tid & 3) * 8;

#define OP_LOAD(dA, dY, k0_) do {                                            \
        const float* gA = Wp + (size_t)((k0_) + kb * 8) * 512 + c0 + mh * 2; \
        _Pragma("unroll")                                                    \
        for (int j = 0; j < 8; ++j)                                          \
            dA[j] = *reinterpret_cast<const f2v*>(gA + j * 512);             \
        _Pragma("unroll")                                                    \
        for (int it = 0; it < 2; ++it)                                       \
            dY[it] = *reinterpret_cast<const s8v*>(                          \
                YH + (size_t)(m0 + br + it * 64) * 512 + (k0_) + bq4);       \
    } while (0)

#define OP_WRITE(bufi, sA, sY) do {                                          \
        _Pragma("unroll")                                                    \
        for (int e = 0; e < 2; ++e) {                                        \
            u32x4 pa;                                                        \
            _Pragma("unroll")                                                \
            for (int jj = 0; jj < 4; ++jj)                                   \
                pa[jj] = cvtpk(sA[jj * 2][e], sA[jj * 2 + 1][e]);            \
            *(u32x4*)((char*)&Al[bufi][0] + swb(mh * 2 + e, kb * 16)) = pa;  \
        }                                                                    \
        _Pragma("unroll")                                                    \
        for (int it = 0; it < 2; ++it)                                       \
            *reinterpret_cast<s8v*>(&Bl[bufi][br + it * 64][bq4]) = sY[it];  \
    } while (0)

#define OP_MFMA(bufi) do {                                                   \
        s8v af[4], bfr[4];                                                   \
        _Pragma("unroll")                                                    \
        for (int mi = 0; mi < 4; ++mi)                                       \
            af[mi] = *(const s8v*)((const char*)&Al[bufi][0]                 \
                                   + swb(wr + mi * 16 + cl, rl * 16));       \
        _Pragma("unroll")                                                    \
        for (int ni = 0; ni < 4; ++ni)                                       \
            bfr[ni] = *reinterpret_cast<const s8v*>(                         \
                &Bl[bufi][wc + ni * 16 + cl][rl * 8]);                       \
        _Pragma("unroll")                                                    \
        for (int mi = 0; mi < 4; ++mi)                                       \
            _Pragma("unroll")                                                \
            for (int ni = 0; ni < 4; ++ni)                                   \
                acc[mi][ni] = MFMA(af[mi], bfr[ni], acc[mi][ni]);            \
    } while (0)

    OP_LOAD(wa0, sy0, 0);
    OP_WRITE(0, wa0, sy0);
    OP_LOAD(wa1, sy1, 32);
    __syncthreads();

    #pragma unroll
    for (int it = 0; it < 8; ++it) {
        const int t = it * 2;
        OP_WRITE(1, wa1, sy1);
        if (t + 2 < 16) OP_LOAD(wa0, sy0, (t + 2) * 32);
        OP_MFMA(0);
        __syncthreads();
        if (t + 2 < 16) OP_WRITE(0, wa0, sy0);
        if (t + 3 < 16) OP_LOAD(wa1, sy1, (t + 3) * 32);
        OP_MFMA(1);
        __syncthreads();
    }
#undef OP_LOAD
#undef OP_WRITE
#undef OP_MFMA

    #pragma unroll
    for (int mi = 0; mi < 4; ++mi)
        #pragma unroll
        for (int r = 0; r < 4; ++r) {
            const int c = c0 + wr + mi * 16 + rl * 4 + r;   // D row = cout
            const float bv = bp[c];
            #pragma unroll
            for (int ni = 0; ni < 4; ++ni) {
                const int tok = m0 + wc + ni * 16 + cl;     // D col = token
                const int bb = tok >> 11, t = tok & 2047;
                const int vv = t >> 8, hw = t & 255;
                out[(size_t)(vv * 4 + bb) * 131072 + (size_t)c * 256 + hw] =
                    acc[mi][ni][r] + bv;
            }
        }
}

// ---------------------------------------------------------------------------
extern "C" void kernel_launch(void* const* d_in, const int* in_sizes, int n_in,
                              void* d_out, int out_size, void* d_ws, size_t ws_size,
                              hipStream_t stream)
{
    const float* q   = (const float*)d_in[0];
    const float* kv  = (const float*)d_in[1];
    const float* Wq  = (const float*)d_in[2];
    const float* bq  = (const float*)d_in[3];
    const float* Wkv = (const float*)d_in[4];
    const float* bkv = (const float*)d_in[5];
    const float* Wp  = (const float*)d_in[6];
    const float* bp  = (const float*)d_in[7];
    float* out = (float*)d_out;

    u16* ws = (u16*)d_ws;
    u16* QH = ws;                    // [4][8][2048][64] bf16, prescaled Q
    u16* KH = QH + 4194304;          // [4][8][2048][64]
    u16* VT = KH + 4194304;          // [4][8][64][2048]
    u16* YH = VT + 4194304;          // [4][2048][512]
    u16* Opart = YH + 4194304;       // [1280][128][64] bf16 = 20 MB
    float* ML  = (float*)(Opart + 10485760);  // [1280][128] f32 = 0.66 MB

    hipLaunchKernelGGL(qkv_proj, dim3(768), dim3(256), 0, stream,
                       q, kv, Wq, bq, Wkv, bkv, QH, KH, VT);
    hipLaunchKernelGGL(attn_part, dim3(1280), dim3(256), 0, stream,
                       QH, KH, VT, Opart, ML);
    hipLaunchKernelGGL(attn_combine, dim3(512), dim3(256), 0, stream,
                       Opart, ML, YH);
    hipLaunchKernelGGL(out_proj, dim3(256), dim3(256), 0, stream, YH, Wp, bp, out);
}